// Round 1
// baseline (231.903 us; speedup 1.0000x reference)
//
#include <hip/hip_runtime.h>
#include <hip/hip_bf16.h>

// Hmoe: gate = sigmoid(x @ w + b); tree-product over 6 levels -> P (32768 x 64);
// out = P @ responses.
// Kernel 1: convert+transpose responses -> RT bf16 [2048][64] (ws)
// Kernel 2: fused gate GEMM (bf16 MFMA, w split hi/lo for precision) + sigmoid
//           + leaf-prob tree -> P bf16 [32768][64] (ws)
// Kernel 3: out = P @ RT via bf16 MFMA, f32 out.

typedef short bf16x8 __attribute__((ext_vector_type(8)));
typedef float f32x4  __attribute__((ext_vector_type(4)));

#define BS    32768
#define DIMX  2048
#define NODES 63
#define NL    64
#define DIMY  2048

__device__ __forceinline__ unsigned short f2bf(float f) {
    union { float f; unsigned int u; } v; v.f = f;
    unsigned int r = v.u + 0x7FFFu + ((v.u >> 16) & 1u);   // round-to-nearest-even
    return (unsigned short)(r >> 16);
}
__device__ __forceinline__ float bf2f(unsigned short h) {
    union { float f; unsigned int u; } v; v.u = ((unsigned int)h) << 16;
    return v.f;
}

// ---------------- kernel 1: responses f32 [64][2048] -> RT bf16 [2048][64] ----
__global__ __launch_bounds__(256) void rt_conv(const float* __restrict__ R,
                                               unsigned short* __restrict__ RT) {
    int f = blockIdx.x * 256 + threadIdx.x;     // 131072 total
    int n = f >> 6;
    int k = f & 63;
    RT[f] = f2bf(R[k * DIMY + n]);              // writes coalesced, reads strided (tiny, L2)
}

// ---------------- kernel 2: gates + tree -> P --------------------------------
#define AM  64      // rows per block
#define AK  64      // K tile
#define ALD 72      // padded LDS row (bf16): 144B = 16B aligned, bank-adv 4

__global__ __launch_bounds__(256) void gate_kernel(const float* __restrict__ x,
                                                   const float* __restrict__ w,
                                                   const float* __restrict__ b,
                                                   unsigned short* __restrict__ P) {
    __shared__ __align__(16) unsigned short xs[AM][ALD];   // x tile bf16
    __shared__ __align__(16) unsigned short wh[NL][ALD];   // w^T hi
    __shared__ __align__(16) unsigned short wl[NL][ALD];   // w^T lo
    __shared__ float gl[AM][NL + 1];                       // gates (pad +1)
    __shared__ float bl[NL];

    const int t  = threadIdx.x;
    const int m0 = blockIdx.x * AM;
    if (t < NL) bl[t] = (t < NODES) ? b[t] : 0.0f;

    const int lane = t & 63;
    const int wv   = t >> 6;        // 4 waves
    const int lr   = lane & 15;
    const int lg   = lane >> 4;
    const int r0   = wv * 16;       // each wave owns 16 rows

    f32x4 acc[4];
    #pragma unroll
    for (int cf = 0; cf < 4; ++cf) acc[cf] = (f32x4){0.f, 0.f, 0.f, 0.f};

    for (int k0 = 0; k0 < DIMX; k0 += AK) {
        __syncthreads();
        // stage x tile: 64 rows x 64 k (f32 -> bf16). 1024 float4 chunks.
        #pragma unroll
        for (int p = 0; p < 4; ++p) {
            int c   = p * 256 + t;
            int row = c >> 4;
            int c4  = c & 15;
            const float4 v = *(const float4*)&x[(size_t)(m0 + row) * DIMX + k0 + c4 * 4];
            ushort4 h;
            h.x = f2bf(v.x); h.y = f2bf(v.y); h.z = f2bf(v.z); h.w = f2bf(v.w);
            *(ushort4*)&xs[row][c4 * 4] = h;
        }
        // stage w tile transposed, split hi/lo: w[k0..k0+63][0..62], flat contiguous
        const int fbase = k0 * NODES;
        for (int f = t; f < AK * NODES; f += 256) {
            int kl = f / 63;
            int j  = f - kl * 63;
            float v = w[fbase + f];
            unsigned short h = f2bf(v);
            wh[j][kl] = h;
            wl[j][kl] = f2bf(v - bf2f(h));
        }
        __syncthreads();
        #pragma unroll
        for (int kk = 0; kk < AK; kk += 32) {
            bf16x8 a = *(const bf16x8*)&xs[r0 + lr][kk + lg * 8];
            #pragma unroll
            for (int cf = 0; cf < 4; ++cf) {
                bf16x8 bh = *(const bf16x8*)&wh[cf * 16 + lr][kk + lg * 8];
                bf16x8 bo = *(const bf16x8*)&wl[cf * 16 + lr][kk + lg * 8];
                acc[cf] = __builtin_amdgcn_mfma_f32_16x16x32_bf16(a, bh, acc[cf], 0, 0, 0);
                acc[cf] = __builtin_amdgcn_mfma_f32_16x16x32_bf16(a, bo, acc[cf], 0, 0, 0);
            }
        }
    }
    __syncthreads();
    // bias + sigmoid -> gates in LDS.  D-frag: row=(lane>>4)*4+reg, col=lane&15.
    #pragma unroll
    for (int cf = 0; cf < 4; ++cf) {
        #pragma unroll
        for (int i = 0; i < 4; ++i) {
            int row = r0 + lg * 4 + i;
            int col = cf * 16 + lr;
            float s = acc[cf][i] + bl[col];
            gl[row][col] = 1.0f / (1.0f + __expf(-s));
        }
    }
    __syncthreads();
    // leaf probabilities: lane handles row r0+(lane>>2), leaves L = m + 16*b4 + 32*b5
    {
        const int rr = r0 + (lane >> 2);
        const int b4 = lane & 1, b5 = (lane >> 1) & 1;
        const float* g = gl[rr];
        float a2[2], a4[4], a8[8], a16[16];
        float g0 = g[0];
        a2[0] = g0; a2[1] = 1.f - g0;
        #pragma unroll
        for (int m = 0; m < 4; ++m) {
            float gg = g[1 + (m & 1)];
            a4[m] = a2[m & 1] * ((m & 2) ? (1.f - gg) : gg);
        }
        #pragma unroll
        for (int m = 0; m < 8; ++m) {
            float gg = g[3 + (m & 3)];
            a8[m] = a4[m & 3] * ((m & 4) ? (1.f - gg) : gg);
        }
        #pragma unroll
        for (int m = 0; m < 16; ++m) {
            float gg = g[7 + (m & 7)];
            a16[m] = a8[m & 7] * ((m & 8) ? (1.f - gg) : gg);
        }
        unsigned short o[16];
        #pragma unroll
        for (int m = 0; m < 16; ++m) {
            float p = a16[m];
            float g5 = g[15 + m];                 // level 5: node 15 + (L&15)
            p *= b4 ? (1.f - g5) : g5;
            float g6 = g[31 + m + 16 * b4];       // level 6: node 31 + (L&31)
            p *= b5 ? (1.f - g6) : g6;
            o[m] = f2bf(p);
        }
        uint4 q0, q1;
        q0.x = (unsigned)o[0]  | ((unsigned)o[1]  << 16);
        q0.y = (unsigned)o[2]  | ((unsigned)o[3]  << 16);
        q0.z = (unsigned)o[4]  | ((unsigned)o[5]  << 16);
        q0.w = (unsigned)o[6]  | ((unsigned)o[7]  << 16);
        q1.x = (unsigned)o[8]  | ((unsigned)o[9]  << 16);
        q1.y = (unsigned)o[10] | ((unsigned)o[11] << 16);
        q1.z = (unsigned)o[12] | ((unsigned)o[13] << 16);
        q1.w = (unsigned)o[14] | ((unsigned)o[15] << 16);
        uint4* dst = (uint4*)&P[(size_t)(m0 + rr) * NL + 16 * b4 + 32 * b5];
        dst[0] = q0;
        dst[1] = q1;
    }
}

// ---------------- kernel 3: out = P @ RT^T (P: MxK=64, RT: [n][k]) -----------
#define BM  128
#define BN  128
#define BLD 72

__global__ __launch_bounds__(256) void out_kernel(const unsigned short* __restrict__ P,
                                                  const unsigned short* __restrict__ RT,
                                                  float* __restrict__ out) {
    __shared__ __align__(16) unsigned short ps[BM][BLD];
    __shared__ __align__(16) unsigned short rs[BN][BLD];
    const int t  = threadIdx.x;
    const int n0 = blockIdx.x * BN;
    const int m0 = blockIdx.y * BM;

    // stage P tile (128x64) and RT tile (128x64): 1024 16B chunks each
    #pragma unroll
    for (int p = 0; p < 4; ++p) {
        int c   = p * 256 + t;
        int row = c >> 3;
        int c8  = c & 7;
        *(uint4*)&ps[row][c8 * 8] = *(const uint4*)&P [(size_t)(m0 + row) * NL + c8 * 8];
        *(uint4*)&rs[row][c8 * 8] = *(const uint4*)&RT[(size_t)(n0 + row) * NL + c8 * 8];
    }
    __syncthreads();

    const int lane = t & 63;
    const int wv   = t >> 6;
    const int wm   = (wv >> 1) * 64;   // wave tile 64x64
    const int wn   = (wv & 1) * 64;
    const int lr   = lane & 15;
    const int lg   = lane >> 4;

    f32x4 acc[4][4];
    #pragma unroll
    for (int rf = 0; rf < 4; ++rf)
        #pragma unroll
        for (int cf = 0; cf < 4; ++cf) acc[rf][cf] = (f32x4){0.f, 0.f, 0.f, 0.f};

    #pragma unroll
    for (int kk = 0; kk < NL; kk += 32) {
        bf16x8 a[4], bb[4];
        #pragma unroll
        for (int rf = 0; rf < 4; ++rf)
            a[rf] = *(const bf16x8*)&ps[wm + rf * 16 + lr][kk + lg * 8];
        #pragma unroll
        for (int cf = 0; cf < 4; ++cf)
            bb[cf] = *(const bf16x8*)&rs[wn + cf * 16 + lr][kk + lg * 8];
        #pragma unroll
        for (int rf = 0; rf < 4; ++rf)
            #pragma unroll
            for (int cf = 0; cf < 4; ++cf)
                acc[rf][cf] = __builtin_amdgcn_mfma_f32_16x16x32_bf16(a[rf], bb[cf],
                                                                      acc[rf][cf], 0, 0, 0);
    }

    #pragma unroll
    for (int rf = 0; rf < 4; ++rf) {
        #pragma unroll
        for (int cf = 0; cf < 4; ++cf) {
            #pragma unroll
            for (int i = 0; i < 4; ++i) {
                int row = m0 + wm + rf * 16 + lg * 4 + i;
                int col = n0 + wn + cf * 16 + lr;
                out[(size_t)row * DIMY + col] = acc[rf][cf][i];
            }
        }
    }
}

extern "C" void kernel_launch(void* const* d_in, const int* in_sizes, int n_in,
                              void* d_out, int out_size, void* d_ws, size_t ws_size,
                              hipStream_t stream) {
    const float* x = (const float*)d_in[0];
    const float* w = (const float*)d_in[1];
    const float* b = (const float*)d_in[2];
    const float* R = (const float*)d_in[3];
    float* out = (float*)d_out;

    unsigned short* P  = (unsigned short*)d_ws;                               // 4 MB
    unsigned short* RT = (unsigned short*)((char*)d_ws + (size_t)BS * NL * 2); // 256 KB

    rt_conv<<<dim3((NL * DIMY) / 256), 256, 0, stream>>>(R, RT);
    gate_kernel<<<dim3(BS / AM), 256, 0, stream>>>(x, w, b, P);
    out_kernel<<<dim3(DIMY / BN, BS / BM), 256, 0, stream>>>(P, RT, out);
}